// Round 1
// baseline (309.538 us; speedup 1.0000x reference)
//
#include <hip/hip_runtime.h>

#define NFREQ   257
#define NFRAMES 3751
#define NS      480000
#define HOP     128
#define WIN     512
#define PADL    256

#define BM 64      // freq tile
#define BN 256     // frame tile (64 per wave)
#define BK 64      // K stage

typedef __attribute__((ext_vector_type(8))) short short8;
typedef __attribute__((ext_vector_type(4))) float f32x4;

__device__ __forceinline__ short f2bf(float f) {
    __bf16 b = (__bf16)f;                 // RNE; compiler pairs into v_cvt_pk_bf16_f32
    return __builtin_bit_cast(short, b);
}

// swizzled byte offset inside a [rows][64] bf16 tile (row stride 128B)
// XOR bank-swizzle per G4: bijective within each 8-row stripe, keeps 16B align
__device__ __forceinline__ int swz(int row, int colByte) {
    return row * 128 + (colByte ^ ((row & 7) << 4));
}

__global__ __launch_bounds__(256, 2)
void stft_mfma_kernel(const float* __restrict__ x,
                      const float* __restrict__ basis,
                      float* __restrict__ out)
{
    __shared__ __align__(16) char smem[49152];
    char* const ar = smem;           //  8 KB: A_real  [64][64] bf16 (swizzled)
    char* const ai = smem + 8192;    //  8 KB: A_imag  [64][64] bf16
    char* const xs = smem + 16384;   // 32 KB: frames X[256][64] bf16

    const int tid  = threadIdx.x;
    const int wave = tid >> 6;
    const int lane = tid & 63;

    const int t0 = blockIdx.x * BN;
    const int f0 = blockIdx.y * BM;
    const int b  = blockIdx.z;

    const float* __restrict__ xb = x + (size_t)b * NS;

    f32x4 accR[4][4], accI[4][4];
    #pragma unroll
    for (int i = 0; i < 4; ++i)
        #pragma unroll
        for (int j = 0; j < 4; ++j) {
            accR[i][j] = f32x4{0.f, 0.f, 0.f, 0.f};
            accI[i][j] = f32x4{0.f, 0.f, 0.f, 0.f};
        }

    for (int ks = 0; ks < WIN; ks += BK) {
        __syncthreads();   // previous iter's LDS readers done

        // ---- stage A_real / A_imag: 64 rows x 8 colgroups = 512 slots ----
        #pragma unroll
        for (int it = 0; it < 2; ++it) {
            int s   = tid + it * 256;
            int row = s >> 3, c = s & 7;
            int fr  = f0 + row;
            short8 vr, vi;
            if (fr < NFREQ) {
                const float4* pr = reinterpret_cast<const float4*>(basis + (size_t)fr * WIN + ks + c * 8);
                const float4* pi = reinterpret_cast<const float4*>(basis + (size_t)(NFREQ + fr) * WIN + ks + c * 8);
                float4 r0 = pr[0], r1 = pr[1];
                float4 q0 = pi[0], q1 = pi[1];
                vr[0]=f2bf(r0.x); vr[1]=f2bf(r0.y); vr[2]=f2bf(r0.z); vr[3]=f2bf(r0.w);
                vr[4]=f2bf(r1.x); vr[5]=f2bf(r1.y); vr[6]=f2bf(r1.z); vr[7]=f2bf(r1.w);
                vi[0]=f2bf(q0.x); vi[1]=f2bf(q0.y); vi[2]=f2bf(q0.z); vi[3]=f2bf(q0.w);
                vi[4]=f2bf(q1.x); vi[5]=f2bf(q1.y); vi[6]=f2bf(q1.z); vi[7]=f2bf(q1.w);
            } else {
                #pragma unroll
                for (int j = 0; j < 8; ++j) { vr[j] = 0; vi[j] = 0; }
            }
            int off = swz(row, c * 16);
            *reinterpret_cast<short8*>(ar + off) = vr;
            *reinterpret_cast<short8*>(ai + off) = vi;
        }

        // ---- stage X: 256 rows x 8 colgroups = 2048 slots ----
        #pragma unroll
        for (int it = 0; it < 8; ++it) {
            int s   = tid + it * 256;
            int row = s >> 3, c = s & 7;
            int p0  = (t0 + row) * HOP + ks + c * 8;   // padded coordinate
            int ix  = p0 - PADL;
            short8 v;
            if (ix >= 0 && ix + 8 <= NS) {             // interior fast path (32B-aligned)
                const float4* p = reinterpret_cast<const float4*>(xb + ix);
                float4 a0 = p[0], a1 = p[1];
                v[0]=f2bf(a0.x); v[1]=f2bf(a0.y); v[2]=f2bf(a0.z); v[3]=f2bf(a0.w);
                v[4]=f2bf(a1.x); v[5]=f2bf(a1.y); v[6]=f2bf(a1.z); v[7]=f2bf(a1.w);
            } else {                                   // reflect boundary
                #pragma unroll
                for (int j = 0; j < 8; ++j) {
                    int idx = ix + j;
                    idx = idx < 0 ? -idx : idx;
                    idx = idx >= NS ? 2 * NS - 2 - idx : idx;
                    v[j] = f2bf(xb[idx]);
                }
            }
            *reinterpret_cast<short8*>(xs + swz(row, c * 16)) = v;
        }

        __syncthreads();

        // ---- compute: two 32-k MFMA steps ----
        #pragma unroll
        for (int ko = 0; ko < 2; ++ko) {
            const int kb = ko * 64 + (lane >> 4) * 16;  // byte col of this lane's 8 bf16
            short8 aR[4], aI[4], xv[4];
            #pragma unroll
            for (int mf = 0; mf < 4; ++mf) {
                int row = mf * 16 + (lane & 15);
                int off = swz(row, kb);
                aR[mf] = *reinterpret_cast<const short8*>(ar + off);
                aI[mf] = *reinterpret_cast<const short8*>(ai + off);
            }
            #pragma unroll
            for (int nt = 0; nt < 4; ++nt) {
                int row = wave * 64 + nt * 16 + (lane & 15);
                xv[nt] = *reinterpret_cast<const short8*>(xs + swz(row, kb));
            }
            #pragma unroll
            for (int mf = 0; mf < 4; ++mf)
                #pragma unroll
                for (int nt = 0; nt < 4; ++nt) {
                    accR[mf][nt] = __builtin_amdgcn_mfma_f32_16x16x32_bf16(aR[mf], xv[nt], accR[mf][nt], 0, 0, 0);
                    accI[mf][nt] = __builtin_amdgcn_mfma_f32_16x16x32_bf16(aI[mf], xv[nt], accI[mf][nt], 0, 0, 0);
                }
        }
    }

    // ---- epilogue: magnitude + masked store ----
    // C/D layout (verified m89/m91): col = lane&15 (frame), row = (lane>>4)*4 + reg (freq)
    const int tBase = t0 + wave * 64 + (lane & 15);
    const int fBase = f0 + (lane >> 4) * 4;
    #pragma unroll
    for (int mf = 0; mf < 4; ++mf) {
        #pragma unroll
        for (int nt = 0; nt < 4; ++nt) {
            int t = tBase + nt * 16;
            if (t >= NFRAMES) continue;
            #pragma unroll
            for (int r = 0; r < 4; ++r) {
                int f = fBase + mf * 16 + r;
                if (f < NFREQ) {
                    float vr = accR[mf][nt][r], vi = accI[mf][nt][r];
                    out[((size_t)b * NFREQ + f) * NFRAMES + t] = sqrtf(vr * vr + vi * vi);
                }
            }
        }
    }
}

extern "C" void kernel_launch(void* const* d_in, const int* in_sizes, int n_in,
                              void* d_out, int out_size, void* d_ws, size_t ws_size,
                              hipStream_t stream) {
    const float* x     = (const float*)d_in[0];
    const float* basis = (const float*)d_in[1];
    float* out = (float*)d_out;
    const int batch = in_sizes[0] / NS;   // 32
    dim3 grid((NFRAMES + BN - 1) / BN,    // 15 frame tiles
              (NFREQ   + BM - 1) / BM,    // 5 freq tiles
              batch);
    stft_mfma_kernel<<<grid, 256, 0, stream>>>(x, basis, out);
}